// Round 2
// baseline (1441.179 us; speedup 1.0000x reference)
//
#include <hip/hip_runtime.h>
#include <hip/hip_bf16.h>

using u16 = unsigned short;
using short8 = __attribute__((ext_vector_type(8))) short;
using floatx4 = __attribute__((ext_vector_type(4))) float;

#define DEVI static __device__ __forceinline__

constexpr int cB = 4, cN = 4096, cD = 768, cE = 4, cS = 1024, cH = 3072;
constexpr int cES = cE * cS; // 4096
constexpr int cHC = cH / 2;  // 1536 H-chunk

DEVI u16 f2bf(float f) {
  union { float f; unsigned u; } v; v.f = f;
  unsigned r = v.u + 0x7fffu + ((v.u >> 16) & 1u); // RNE
  return (u16)(r >> 16);
}
DEVI float bf2f(u16 b) {
  union { unsigned u; float f; } v; v.u = ((unsigned)b) << 16;
  return v.f;
}
DEVI float gelu_tanh(float x) {
  // jax.nn.gelu default: approximate=True (tanh form)
  float z = 1.5957691216057308f * (x + 0.044715f * x * x * x);
  z = fminf(fmaxf(z, -30.f), 30.f);
  float e = __expf(z);
  float t = (e - 1.f) / (e + 1.f);
  return 0.5f * x * (1.f + t);
}

// ---------------- zero fp32 buffer ----------------
__global__ __launch_bounds__(256) void zero_kernel(float* __restrict__ p, int n) {
  int i = blockIdx.x * 256 + threadIdx.x;
  if (i < n) p[i] = 0.f;
}

// ---------------- elementwise convert f32 -> bf16 ----------------
__global__ __launch_bounds__(256) void convert_kernel(const float* __restrict__ in,
                                                      u16* __restrict__ out, long n) {
  long stride = (long)gridDim.x * 256 * 4;
  for (long idx = ((long)blockIdx.x * 256 + threadIdx.x) * 4; idx < n; idx += stride) {
    float4 v = *(const float4*)(in + idx);
    ushort4 o;
    o.x = f2bf(v.x); o.y = f2bf(v.y); o.z = f2bf(v.z); o.w = f2bf(v.w);
    *(ushort4*)(out + idx) = o;
  }
}

// ---------------- batched transpose [R][C] -> [C][R], output bf16 ----------------
DEVI u16 to_bf(float f) { return f2bf(f); }
DEVI u16 to_bf(u16 u) { return u; }

template <typename Tin>
__global__ __launch_bounds__(256) void transpose_bf16_kernel(const Tin* __restrict__ in,
                                                             u16* __restrict__ out,
                                                             int R, int C,
                                                             long strideIn, long strideOut) {
  __shared__ u16 tile[64][65];
  const Tin* inb = in + (long)blockIdx.z * strideIn;
  u16* outb = out + (long)blockIdx.z * strideOut;
  const int r0 = blockIdx.y * 64, c0 = blockIdx.x * 64;
  const int tid = threadIdx.x;
#pragma unroll
  for (int i = 0; i < 16; i++) {
    int idx = i * 256 + tid;
    int r = idx >> 6, c = idx & 63;
    tile[r][c] = to_bf(inb[(long)(r0 + r) * C + (c0 + c)]);
  }
  __syncthreads();
#pragma unroll
  for (int i = 0; i < 16; i++) {
    int idx = i * 256 + tid;
    int r = idx >> 6, c = idx & 63;
    outb[(long)(c0 + r) * R + (r0 + c)] = tile[c][r];
  }
}

// ---------------- Z2: row sums (one block per row) ----------------
__global__ __launch_bounds__(256) void rowsum_kernel(const u16* __restrict__ P,
                                                     float* __restrict__ Z, int cols) {
  long base = (long)blockIdx.x * cols;
  int tid = threadIdx.x;
  float s = 0.f;
  for (int c = tid * 4; c < cols; c += 256 * 4) {
    ushort4 v = *(const ushort4*)(P + base + c);
    s += bf2f(v.x) + bf2f(v.y) + bf2f(v.z) + bf2f(v.w);
  }
  for (int o = 32; o > 0; o >>= 1) s += __shfl_down(s, o, 64);
  __shared__ float ws4[4];
  if ((tid & 63) == 0) ws4[tid >> 6] = s;
  __syncthreads();
  if (tid == 0) Z[blockIdx.x] = ws4[0] + ws4[1] + ws4[2] + ws4[3];
}

// ---------------- Z1: column sums, chunked + atomic (Z pre-zeroed) ----------------
__global__ __launch_bounds__(256) void colsum_kernel(const u16* __restrict__ P,
                                                     float* __restrict__ Z, int cols) {
  int col = blockIdx.x * 256 + threadIdx.x;
  int r0 = blockIdx.y * 256;
  float s = 0.f;
  for (int r = r0; r < r0 + 256; r++) s += bf2f(P[(long)r * cols + col]);
  atomicAdd(Z + col, s);
}

// ---------------- NT GEMM: C[m][n] = sum_k A[m][k] * B[n][k], bf16 MFMA ----------------
// EPI: 0 exp->bf16
//      1 v/rowVec->bf16
//      2 gelu(v+colVec)->bf16
//      3 v+colVec->bf16
//      4 v/rowVec->f32
//      5 v+prevC->bf16 (read-accumulate)
template <int EPI>
__global__ __launch_bounds__(256, 2) void gemm_nt(const u16* __restrict__ A,
                                                  const u16* __restrict__ Bm,
                                                  void* __restrict__ Cout,
                                                  int M, int Nn, int K,
                                                  long ldA, long ldB, long ldC,
                                                  long strideA, long strideB, int modB,
                                                  long strideC,
                                                  const float* __restrict__ epiVec,
                                                  long epiStride, int epiMod) {
  __shared__ u16 As[128][40]; // +8 pad: 80B row stride, 16B aligned
  __shared__ u16 Bs[128][40];
  const int bz = blockIdx.z;
  const u16* Ab = A + (long)bz * strideA;
  const u16* Bb = Bm + (long)(bz % modB) * strideB;
  const float* ev = epiVec + (long)(bz % epiMod) * epiStride;
  const int tileM = blockIdx.y * 128, tileN = blockIdx.x * 128;
  const int tid = threadIdx.x;
  const int wave = tid >> 6, lane = tid & 63;
  const int quad = lane >> 4, l16 = lane & 15;
  const int wm = (wave >> 1) * 64, wn = (wave & 1) * 64;

  // staging: 512 vec8 per tile, 2 per thread
  const int ar0 = tid >> 2, ak0 = (tid & 3) * 8;
  const int ar1 = (tid + 256) >> 2, ak1 = ((tid + 256) & 3) * 8;

  const long aOff0 = (long)(tileM + ar0) * ldA + ak0;
  const long aOff1 = (long)(tileM + ar1) * ldA + ak1;
  const long bOff0 = (long)(tileN + ar0) * ldB + ak0;
  const long bOff1 = (long)(tileN + ar1) * ldB + ak1;

  uint4 aR0 = *(const uint4*)(Ab + aOff0);
  uint4 aR1 = *(const uint4*)(Ab + aOff1);
  uint4 bR0 = *(const uint4*)(Bb + bOff0);
  uint4 bR1 = *(const uint4*)(Bb + bOff1);

  floatx4 acc[4][4] = {};

  for (int k0 = 0; k0 < K; k0 += 32) {
    __syncthreads();
    *(uint4*)&As[ar0][ak0] = aR0;
    *(uint4*)&As[ar1][ak1] = aR1;
    *(uint4*)&Bs[ar0][ak0] = bR0;
    *(uint4*)&Bs[ar1][ak1] = bR1;
    __syncthreads();
    const int kn = k0 + 32;
    if (kn < K) { // prefetch next chunk; overlaps with MFMA below
      aR0 = *(const uint4*)(Ab + aOff0 + kn);
      aR1 = *(const uint4*)(Ab + aOff1 + kn);
      bR0 = *(const uint4*)(Bb + bOff0 + kn);
      bR1 = *(const uint4*)(Bb + bOff1 + kn);
    }
    short8 af[4], bq[4];
#pragma unroll
    for (int i = 0; i < 4; i++) af[i] = *(const short8*)&As[wm + i * 16 + l16][quad * 8];
#pragma unroll
    for (int j = 0; j < 4; j++) bq[j] = *(const short8*)&Bs[wn + j * 16 + l16][quad * 8];
#pragma unroll
    for (int i = 0; i < 4; i++)
#pragma unroll
      for (int j = 0; j < 4; j++)
        acc[i][j] = __builtin_amdgcn_mfma_f32_16x16x32_bf16(af[i], bq[j], acc[i][j], 0, 0, 0);
  }

  // C/D layout: col = lane&15, row = quad*4 + r  (m89/m91-verified)
  const long cBase = (long)bz * strideC;
#pragma unroll
  for (int i = 0; i < 4; i++) {
#pragma unroll
    for (int r = 0; r < 4; r++) {
      const int row = tileM + wm + i * 16 + quad * 4 + r;
      float rscale = 1.f;
      if (EPI == 1 || EPI == 4) rscale = 1.f / ev[row];
#pragma unroll
      for (int j = 0; j < 4; j++) {
        const int col = tileN + wn + j * 16 + l16;
        float v = acc[i][j][r];
        const long cIdx = cBase + (long)row * ldC + col;
        if (EPI == 0) v = __expf(v);
        if (EPI == 1 || EPI == 4) v *= rscale;
        if (EPI == 2) v = gelu_tanh(v + ev[col]);
        if (EPI == 3) v = v + ev[col];
        if (EPI == 5) v = v + bf2f(((u16*)Cout)[cIdx]);
        if (EPI == 4)
          ((float*)Cout)[cIdx] = v;
        else
          ((u16*)Cout)[cIdx] = f2bf(v);
      }
    }
  }
}

extern "C" void kernel_launch(void* const* d_in, const int* in_sizes, int n_in,
                              void* d_out, int out_size, void* d_ws, size_t ws_size,
                              hipStream_t stream) {
  const float* x   = (const float*)d_in[0]; // [B,N,D]
  const float* phi = (const float*)d_in[1]; // [E,S,D]
  const float* w1  = (const float*)d_in[2]; // [E,D,H]
  const float* b1  = (const float*)d_in[3]; // [E,H]
  const float* w2  = (const float*)d_in[4]; // [E,H,D]
  const float* b2  = (const float*)d_in[5]; // [E,D]
  (void)in_sizes; (void)n_in; (void)out_size; (void)ws_size;
  float* out_f = (float*)d_out;

  char* ws = (char*)d_ws;
  size_t off = 0;
  auto carve = [&](size_t bytes) -> char* {
    char* p = ws + off;
    off += (bytes + 255) & ~(size_t)255;
    return p;
  };

  // ---- workspace (~187 MB total) ----
  const size_t SZ_P = (size_t)cN * cES * 2; // 33.55 MB
  char* R1 = carve(2 * SZ_P);               // 67.1 MB multi-use region
  u16* Pb  = (u16*)R1;                      // phase A/C: P_b [N][ES]
  u16* Ptb = (u16*)(R1 + SZ_P);             // phase A: Pt_b [ES][N]
  u16* Hc  = (u16*)R1;                      // phase B: H chunk [16][S][1536] (50.3 MB)
  u16* Yt  = (u16*)(R1 + SZ_P);             // phase C: Yt [B][D][ES] (25.2 MB)
  u16* Xbf = (u16*)carve((size_t)cB * cN * cD * 2);   // persistent (phase A + C)
  char* R3 = carve((size_t)cB * cD * cN * 2);
  u16* Xt = (u16*)R3;                       // phase A: [B][D][N]
  u16* Yv = (u16*)R3;                       // phase B/C: [B][ES][D]
  u16* Slots = (u16*)carve((size_t)cB * cES * cD * 2);
  u16* Phibf = (u16*)carve((size_t)cES * cD * 2);     // persistent (recompute)
  u16* W1t = (u16*)carve((size_t)cE * cH * cD * 2);   // [e][h][d]
  u16* W2t = (u16*)carve((size_t)cE * cD * cH * 2);   // [e][d][h]
  float* Z1 = (float*)carve((size_t)cB * cES * 4);
  float* Z2 = (float*)carve((size_t)cB * cN * 4);

  // ---- phase 0: casts / weight transposes ----
  convert_kernel<<<2048, 256, 0, stream>>>(x, Xbf, (long)cB * cN * cD);
  convert_kernel<<<1024, 256, 0, stream>>>(phi, Phibf, (long)cES * cD);
  transpose_bf16_kernel<float><<<dim3(cH / 64, cD / 64, cE), 256, 0, stream>>>(
      w1, W1t, cD, cH, (long)cD * cH, (long)cH * cD);
  transpose_bf16_kernel<float><<<dim3(cD / 64, cH / 64, cE), 256, 0, stream>>>(
      w2, W2t, cH, cD, (long)cH * cD, (long)cD * cH);
  transpose_bf16_kernel<float><<<dim3(cD / 64, cN / 64, cB), 256, 0, stream>>>(
      x, Xt, cN, cD, (long)cN * cD, (long)cD * cN);
  zero_kernel<<<(cB * cES) / 256, 256, 0, stream>>>(Z1, cB * cES);

  // ---- phase A: per batch, P_b -> Z1,Z2 -> Pt_b -> Slots_b ----
  for (int b = 0; b < cB; b++) {
    const u16* Xb = Xbf + (long)b * cN * cD;
    // P_b[n][es] = exp(X_b . Phi^T)
    gemm_nt<0><<<dim3(cES / 128, cN / 128, 1), 256, 0, stream>>>(
        Xb, Phibf, Pb, cN, cES, cD, cD, cD, cES,
        0L, 0L, 1, 0L, Z1, 0, 1);
    colsum_kernel<<<dim3(cES / 256, cN / 256, 1), 256, 0, stream>>>(
        Pb, Z1 + (long)b * cES, cES);
    rowsum_kernel<<<cN, 256, 0, stream>>>(Pb, Z2 + (long)b * cN, cES);
    transpose_bf16_kernel<u16><<<dim3(cES / 64, cN / 64, 1), 256, 0, stream>>>(
        Pb, Ptb, cN, cES, 0L, 0L);
    // Slots_b[es][d] = (Pt_b . Xt_b^T) / Z1_b
    gemm_nt<1><<<dim3(cD / 128, cES / 128, 1), 256, 0, stream>>>(
        Ptb, Xt + (long)b * cD * cN, Slots + (long)b * cES * cD,
        cES, cD, cN, cN, cN, cD,
        0L, 0L, 1, 0L, Z1 + (long)b * cES, 0, 1);
  }

  // ---- phase B: MLP in 2 H-chunks (bz = b*4+e) ----
  for (int hc = 0; hc < 2; hc++) {
    const int h0 = hc * cHC;
    // Hc[bz][s][hchunk] = gelu(Slots . W1t[:, h0:h0+HC]^T + b1[h0:])
    gemm_nt<2><<<dim3(cHC / 128, cS / 128, cB * cE), 256, 0, stream>>>(
        Slots, W1t + (long)h0 * cD, Hc, cS, cHC, cD, cD, cD, cHC,
        (long)cS * cD, (long)cH * cD, cE, (long)cS * cHC, b1 + h0, cH, cE);
    // Yv[bz][s][d] (+)= Hc . W2t[:, h0:h0+HC]^T (+ b2 on first chunk)
    if (hc == 0)
      gemm_nt<3><<<dim3(cD / 128, cS / 128, cB * cE), 256, 0, stream>>>(
          Hc, W2t + h0, Yv, cS, cD, cHC, cHC, cH, cD,
          (long)cS * cHC, (long)cD * cH, cE, (long)cS * cD, b2, cD, cE);
    else
      gemm_nt<5><<<dim3(cD / 128, cS / 128, cB * cE), 256, 0, stream>>>(
          Hc, W2t + h0, Yv, cS, cD, cHC, cHC, cH, cD,
          (long)cS * cHC, (long)cD * cH, cE, (long)cS * cD, b2, cD, cE);
  }

  // ---- phase C: Yt, then per batch recompute P_b and combine ----
  transpose_bf16_kernel<u16><<<dim3(cD / 64, cES / 64, cB), 256, 0, stream>>>(
      Yv, Yt, cES, cD, (long)cES * cD, (long)cD * cES);
  for (int b = 0; b < cB; b++) {
    const u16* Xb = Xbf + (long)b * cN * cD;
    gemm_nt<0><<<dim3(cES / 128, cN / 128, 1), 256, 0, stream>>>(
        Xb, Phibf, Pb, cN, cES, cD, cD, cD, cES,
        0L, 0L, 1, 0L, Z1, 0, 1);
    // out[n][d] = (P_b . Yt_b^T) / Z2_b   (fp32)
    gemm_nt<4><<<dim3(cD / 128, cN / 128, 1), 256, 0, stream>>>(
        Pb, Yt + (long)b * cD * cES, out_f + (long)b * cN * cD,
        cN, cD, cES, cES, cES, cD,
        0L, 0L, 1, 0L, Z2 + (long)b * cN, 0, 1);
  }
}

// Round 3
// 1379.884 us; speedup vs baseline: 1.0444x; 1.0444x over previous
//
#include <hip/hip_runtime.h>
#include <hip/hip_bf16.h>

using u16 = unsigned short;
using short8 = __attribute__((ext_vector_type(8))) short;
using floatx4 = __attribute__((ext_vector_type(4))) float;

#define DEVI static __device__ __forceinline__

constexpr int cB = 4, cN = 4096, cD = 768, cE = 4, cS = 1024, cH = 3072;
constexpr int cES = cE * cS; // 4096
constexpr int cHC = cH / 2;  // 1536 H-chunk

DEVI u16 f2bf(float f) {
  union { float f; unsigned u; } v; v.f = f;
  unsigned r = v.u + 0x7fffu + ((v.u >> 16) & 1u); // RNE
  return (u16)(r >> 16);
}
DEVI float bf2f(u16 b) {
  union { unsigned u; float f; } v; v.u = ((unsigned)b) << 16;
  return v.f;
}
DEVI float gelu_tanh(float x) {
  // jax.nn.gelu default: approximate=True (tanh form)
  float z = 1.5957691216057308f * (x + 0.044715f * x * x * x);
  z = fminf(fmaxf(z, -30.f), 30.f);
  float e = __expf(z);
  float t = (e - 1.f) / (e + 1.f);
  return 0.5f * x * (1.f + t);
}

// async global->LDS, 16B per lane; lds dest = wave-uniform base + lane*16
DEVI void glds16(const u16* g, u16* l) {
  __builtin_amdgcn_global_load_lds(
      (const __attribute__((address_space(1))) void*)g,
      (__attribute__((address_space(3))) void*)l, 16, 0, 0);
}

// ---------------- zero fp32 buffer ----------------
__global__ __launch_bounds__(256) void zero_kernel(float* __restrict__ p, int n) {
  int i = blockIdx.x * 256 + threadIdx.x;
  if (i < n) p[i] = 0.f;
}

// ---------------- elementwise convert f32 -> bf16 ----------------
__global__ __launch_bounds__(256) void convert_kernel(const float* __restrict__ in,
                                                      u16* __restrict__ out, long n) {
  long stride = (long)gridDim.x * 256 * 4;
  for (long idx = ((long)blockIdx.x * 256 + threadIdx.x) * 4; idx < n; idx += stride) {
    float4 v = *(const float4*)(in + idx);
    ushort4 o;
    o.x = f2bf(v.x); o.y = f2bf(v.y); o.z = f2bf(v.z); o.w = f2bf(v.w);
    *(ushort4*)(out + idx) = o;
  }
}

// ---------------- batched transpose [R][C] -> [C][R], output bf16 ----------------
DEVI u16 to_bf(float f) { return f2bf(f); }
DEVI u16 to_bf(u16 u) { return u; }

template <typename Tin>
__global__ __launch_bounds__(256) void transpose_bf16_kernel(const Tin* __restrict__ in,
                                                             u16* __restrict__ out,
                                                             int R, int C,
                                                             long strideIn, long strideOut) {
  __shared__ u16 tile[64][65];
  const Tin* inb = in + (long)blockIdx.z * strideIn;
  u16* outb = out + (long)blockIdx.z * strideOut;
  const int r0 = blockIdx.y * 64, c0 = blockIdx.x * 64;
  const int tid = threadIdx.x;
#pragma unroll
  for (int i = 0; i < 16; i++) {
    int idx = i * 256 + tid;
    int r = idx >> 6, c = idx & 63;
    tile[r][c] = to_bf(inb[(long)(r0 + r) * C + (c0 + c)]);
  }
  __syncthreads();
#pragma unroll
  for (int i = 0; i < 16; i++) {
    int idx = i * 256 + tid;
    int r = idx >> 6, c = idx & 63;
    outb[(long)(c0 + r) * R + (r0 + c)] = tile[c][r];
  }
}

// ---------------- Z2: row sums (one block per row) ----------------
__global__ __launch_bounds__(256) void rowsum_kernel(const u16* __restrict__ P,
                                                     float* __restrict__ Z, int cols) {
  long base = (long)blockIdx.x * cols;
  int tid = threadIdx.x;
  float s = 0.f;
  for (int c = tid * 4; c < cols; c += 256 * 4) {
    ushort4 v = *(const ushort4*)(P + base + c);
    s += bf2f(v.x) + bf2f(v.y) + bf2f(v.z) + bf2f(v.w);
  }
  for (int o = 32; o > 0; o >>= 1) s += __shfl_down(s, o, 64);
  __shared__ float ws4[4];
  if ((tid & 63) == 0) ws4[tid >> 6] = s;
  __syncthreads();
  if (tid == 0) Z[blockIdx.x] = ws4[0] + ws4[1] + ws4[2] + ws4[3];
}

// ---------------- Z1: column sums, chunked + atomic (Z pre-zeroed) ----------------
__global__ __launch_bounds__(256) void colsum_kernel(const u16* __restrict__ P,
                                                     float* __restrict__ Z, int cols) {
  int col = blockIdx.x * 256 + threadIdx.x;
  int r0 = blockIdx.y * 256;
  float s = 0.f;
  for (int r = r0; r < r0 + 256; r++) s += bf2f(P[(long)r * cols + col]);
  atomicAdd(Z + col, s);
}

// ---------------- NT GEMM: C[m][n] = sum_k A[m][k] * B[n][k], bf16 MFMA ----------------
// m97-style engine: global_load_lds width=16 staging, unpadded LDS.
// EPI: 0 exp->bf16
//      1 v/rowVec->bf16
//      2 gelu(v+colVec)->bf16
//      3 v+colVec->bf16
//      4 v/rowVec->f32
//      5 v+prevC->bf16 (read-accumulate)
template <int EPI>
__global__ __launch_bounds__(256, 2) void gemm_nt(const u16* __restrict__ A,
                                                  const u16* __restrict__ Bm,
                                                  void* __restrict__ Cout,
                                                  int M, int Nn, int K,
                                                  long ldA, long ldB, long ldC,
                                                  long strideA, long strideB, int modB,
                                                  long strideC,
                                                  const float* __restrict__ epiVec,
                                                  long epiStride, int epiMod) {
  __shared__ u16 As[128 * 32]; // unpadded: required by global_load_lds lane mapping
  __shared__ u16 Bs[128 * 32];
  const int bz = blockIdx.z;
  const u16* Ab = A + (long)bz * strideA;
  const u16* Bb = Bm + (long)(bz % modB) * strideB;
  const float* ev = epiVec + (long)(bz % epiMod) * epiStride;
  const int tileM = blockIdx.y * 128, tileN = blockIdx.x * 128;
  const int tid = threadIdx.x;
  const int wave = tid >> 6, lane = tid & 63;
  const int quad = lane >> 4, l16 = lane & 15;
  const int wm = (wave >> 1) * 64, wn = (wave & 1) * 64;

  // staging: tile = 128 rows x 32 k = 4096 elems; wave w covers elems
  // [(w*2+c)*512, +512) for chunk c in {0,1}; lane l -> elem base + l*8.
  // LDS linear layout [row*32 + k] == elem index (fills contiguously).
  const int e0 = (wave * 2) * 512 + lane * 8;
  const int e1 = (wave * 2 + 1) * 512 + lane * 8;
  const u16* aG0 = Ab + (long)(tileM + (e0 >> 5)) * ldA + (e0 & 31);
  const u16* aG1 = Ab + (long)(tileM + (e1 >> 5)) * ldA + (e1 & 31);
  const u16* bG0 = Bb + (long)(tileN + (e0 >> 5)) * ldB + (e0 & 31);
  const u16* bG1 = Bb + (long)(tileN + (e1 >> 5)) * ldB + (e1 & 31);
  u16* aL0 = As + (wave * 2) * 512;       // wave-uniform LDS base
  u16* aL1 = As + (wave * 2 + 1) * 512;
  u16* bL0 = Bs + (wave * 2) * 512;
  u16* bL1 = Bs + (wave * 2 + 1) * 512;

  floatx4 acc[4][4] = {};

  for (int kk = 0; kk < K; kk += 32) {
    __syncthreads(); // previous iteration's ds_reads done before overwrite
    glds16(aG0 + kk, aL0);
    glds16(aG1 + kk, aL1);
    glds16(bG0 + kk, bL0);
    glds16(bG1 + kk, bL1);
    __syncthreads(); // compiler drains vmcnt before s_barrier -> LDS valid
    short8 af[4], bq[4];
#pragma unroll
    for (int i = 0; i < 4; i++)
      af[i] = *(const short8*)&As[(wm + i * 16 + l16) * 32 + quad * 8];
#pragma unroll
    for (int j = 0; j < 4; j++)
      bq[j] = *(const short8*)&Bs[(wn + j * 16 + l16) * 32 + quad * 8];
#pragma unroll
    for (int i = 0; i < 4; i++)
#pragma unroll
      for (int j = 0; j < 4; j++)
        acc[i][j] = __builtin_amdgcn_mfma_f32_16x16x32_bf16(af[i], bq[j], acc[i][j], 0, 0, 0);
  }

  // C/D layout: col = lane&15, row = quad*4 + r  (m89/m91-verified)
  const long cBase = (long)bz * strideC;
#pragma unroll
  for (int i = 0; i < 4; i++) {
#pragma unroll
    for (int r = 0; r < 4; r++) {
      const int row = tileM + wm + i * 16 + quad * 4 + r;
      float rscale = 1.f;
      if (EPI == 1 || EPI == 4) rscale = 1.f / ev[row];
#pragma unroll
      for (int j = 0; j < 4; j++) {
        const int col = tileN + wn + j * 16 + l16;
        float v = acc[i][j][r];
        const long cIdx = cBase + (long)row * ldC + col;
        if (EPI == 0) v = __expf(v);
        if (EPI == 1 || EPI == 4) v *= rscale;
        if (EPI == 2) v = gelu_tanh(v + ev[col]);
        if (EPI == 3) v = v + ev[col];
        if (EPI == 5) v = v + bf2f(((u16*)Cout)[cIdx]);
        if (EPI == 4)
          ((float*)Cout)[cIdx] = v;
        else
          ((u16*)Cout)[cIdx] = f2bf(v);
      }
    }
  }
}

extern "C" void kernel_launch(void* const* d_in, const int* in_sizes, int n_in,
                              void* d_out, int out_size, void* d_ws, size_t ws_size,
                              hipStream_t stream) {
  const float* x   = (const float*)d_in[0]; // [B,N,D]
  const float* phi = (const float*)d_in[1]; // [E,S,D]
  const float* w1  = (const float*)d_in[2]; // [E,D,H]
  const float* b1  = (const float*)d_in[3]; // [E,H]
  const float* w2  = (const float*)d_in[4]; // [E,H,D]
  const float* b2  = (const float*)d_in[5]; // [E,D]
  (void)in_sizes; (void)n_in; (void)out_size; (void)ws_size;
  float* out_f = (float*)d_out;

  char* ws = (char*)d_ws;
  size_t off = 0;
  auto carve = [&](size_t bytes) -> char* {
    char* p = ws + off;
    off += (bytes + 255) & ~(size_t)255;
    return p;
  };

  // ---- workspace (~187 MB total) ----
  const size_t SZ_P = (size_t)cN * cES * 2; // 33.55 MB
  char* R1 = carve(2 * SZ_P);               // 67.1 MB multi-use region
  u16* Pb  = (u16*)R1;                      // phase A: P_b [N][ES]
  u16* Ptb = (u16*)(R1 + SZ_P);             // phase A: Pt_b [ES][N]
  u16* Hc  = (u16*)R1;                      // phase B: H chunk [16][S][1536] (50.3 MB)
  u16* P2  = (u16*)R1;                      // phase C: P pair [2][N][ES] (67.1 MB)
  u16* Xbf = (u16*)carve((size_t)cB * cN * cD * 2);   // persistent (phase A + C)
  char* R3 = carve((size_t)cB * cD * cN * 2);
  u16* Xt = (u16*)R3;                       // phase A: [B][D][N]
  u16* Yv = (u16*)R3;                       // phase B/C: [B][ES][D]
  char* R4 = carve((size_t)cB * cES * cD * 2);
  u16* Slots = (u16*)R4;                    // phase A/B: [B][ES][D]
  u16* Yt    = (u16*)R4;                    // phase C: [B][D][ES] (same 25.2 MB)
  u16* Phibf = (u16*)carve((size_t)cES * cD * 2);     // persistent (recompute)
  u16* W1t = (u16*)carve((size_t)cE * cH * cD * 2);   // [e][h][d]
  u16* W2t = (u16*)carve((size_t)cE * cD * cH * 2);   // [e][d][h]
  float* Z1 = (float*)carve((size_t)cB * cES * 4);
  float* Z2 = (float*)carve((size_t)cB * cN * 4);

  // ---- phase 0: casts / weight transposes ----
  convert_kernel<<<2048, 256, 0, stream>>>(x, Xbf, (long)cB * cN * cD);
  convert_kernel<<<1024, 256, 0, stream>>>(phi, Phibf, (long)cES * cD);
  transpose_bf16_kernel<float><<<dim3(cH / 64, cD / 64, cE), 256, 0, stream>>>(
      w1, W1t, cD, cH, (long)cD * cH, (long)cH * cD);
  transpose_bf16_kernel<float><<<dim3(cD / 64, cH / 64, cE), 256, 0, stream>>>(
      w2, W2t, cH, cD, (long)cH * cD, (long)cD * cH);
  transpose_bf16_kernel<float><<<dim3(cD / 64, cN / 64, cB), 256, 0, stream>>>(
      x, Xt, cN, cD, (long)cN * cD, (long)cD * cN);
  zero_kernel<<<(cB * cES) / 256, 256, 0, stream>>>(Z1, cB * cES);

  // ---- phase A: per batch, P_b -> Z1,Z2 -> Pt_b -> Slots_b ----
  for (int b = 0; b < cB; b++) {
    const u16* Xb = Xbf + (long)b * cN * cD;
    // P_b[n][es] = exp(X_b . Phi^T)
    gemm_nt<0><<<dim3(cES / 128, cN / 128, 1), 256, 0, stream>>>(
        Xb, Phibf, Pb, cN, cES, cD, cD, cD, cES,
        0L, 0L, 1, 0L, Z1, 0, 1);
    colsum_kernel<<<dim3(cES / 256, cN / 256, 1), 256, 0, stream>>>(
        Pb, Z1 + (long)b * cES, cES);
    rowsum_kernel<<<cN, 256, 0, stream>>>(Pb, Z2 + (long)b * cN, cES);
    transpose_bf16_kernel<u16><<<dim3(cES / 64, cN / 64, 1), 256, 0, stream>>>(
        Pb, Ptb, cN, cES, 0L, 0L);
    // Slots_b[es][d] = (Pt_b . Xt_b^T) / Z1_b
    gemm_nt<1><<<dim3(cD / 128, cES / 128, 1), 256, 0, stream>>>(
        Ptb, Xt + (long)b * cD * cN, Slots + (long)b * cES * cD,
        cES, cD, cN, cN, cN, cD,
        0L, 0L, 1, 0L, Z1 + (long)b * cES, 0, 1);
  }

  // ---- phase B: MLP in 2 H-chunks (bz = b*4+e) ----
  for (int hc = 0; hc < 2; hc++) {
    const int h0 = hc * cHC;
    // Hc[bz][s][hchunk] = gelu(Slots . W1t[:, h0:h0+HC]^T + b1[h0:])
    gemm_nt<2><<<dim3(cHC / 128, cS / 128, cB * cE), 256, 0, stream>>>(
        Slots, W1t + (long)h0 * cD, Hc, cS, cHC, cD, cD, cD, cHC,
        (long)cS * cD, (long)cH * cD, cE, (long)cS * cHC, b1 + h0, cH, cE);
    // Yv[bz][s][d] (+)= Hc . W2t[:, h0:h0+HC]^T (+ b2 on first chunk)
    if (hc == 0)
      gemm_nt<3><<<dim3(cD / 128, cS / 128, cB * cE), 256, 0, stream>>>(
          Hc, W2t + h0, Yv, cS, cD, cHC, cHC, cH, cD,
          (long)cS * cHC, (long)cD * cH, cE, (long)cS * cD, b2, cD, cE);
    else
      gemm_nt<5><<<dim3(cD / 128, cS / 128, cB * cE), 256, 0, stream>>>(
          Hc, W2t + h0, Yv, cS, cD, cHC, cHC, cH, cD,
          (long)cS * cHC, (long)cD * cH, cE, (long)cS * cD, b2, cD, cE);
  }

  // ---- phase C: Yt (into dead Slots region), then b-pairs: recompute P, combine ----
  transpose_bf16_kernel<u16><<<dim3(cD / 64, cES / 64, cB), 256, 0, stream>>>(
      Yv, Yt, cES, cD, (long)cES * cD, (long)cD * cES);
  for (int bp = 0; bp < 2; bp++) {
    const u16* Xb = Xbf + (long)(bp * 2) * cN * cD;
    // P2[z][n][es] = exp(X_{bp*2+z} . Phi^T), z=0,1
    gemm_nt<0><<<dim3(cES / 128, cN / 128, 2), 256, 0, stream>>>(
        Xb, Phibf, P2, cN, cES, cD, cD, cD, cES,
        (long)cN * cD, 0L, 1, (long)cN * cES, Z1, 0, 1);
    // out[z][n][d] = (P2[z] . Yt_{bp*2+z}^T) / Z2   (fp32)
    gemm_nt<4><<<dim3(cD / 128, cN / 128, 2), 256, 0, stream>>>(
        P2, Yt + (long)(bp * 2) * cD * cES, out_f + (long)(bp * 2) * cN * cD,
        cN, cD, cES, cES, cES, cD,
        (long)cN * cES, (long)cD * cES, 2, (long)cN * cD,
        Z2 + (long)(bp * 2) * cN, cN, 2);
  }
}